// Round 1
// baseline (824.131 us; speedup 1.0000x reference)
//
#include <hip/hip_runtime.h>

#define HD 64   // hidden/feature dim (D == H == 64)

// ---------------- degree / norm ----------------

__global__ void init_deg_k(float* deg, int n) {
    int i = blockIdx.x * blockDim.x + threadIdx.x;
    if (i < n) deg[i] = 1.0f;  // self-loop
}

__global__ void deg_edges_k(const int* __restrict__ dst, float* deg, int E) {
    int e = blockIdx.x * blockDim.x + threadIdx.x;
    if (e < E) atomicAdd(&deg[dst[e]], 1.0f);
}

__global__ void finalize_dis_k(float* deg, int n) {
    int i = blockIdx.x * blockDim.x + threadIdx.x;
    if (i < n) deg[i] = 1.0f / sqrtf(deg[i]);
}

// ---------------- 64x64 GEMM: out[n,64] = act(in + b_prev) @ W ----------------
// Fuses the PREVIOUS layer's bias (+ optional relu) into the input load.
#define GROWS 16
__global__ __launch_bounds__(256) void gemm64_k(
    const float* __restrict__ in, const float* __restrict__ b_prev, int relu_prev,
    const float* __restrict__ W, float* __restrict__ out, int n)
{
    __shared__ float Ws[HD * HD];     // 16 KB
    __shared__ float Hs[GROWS * HD];  // 4 KB
    int tid = threadIdx.x;
    for (int i = tid; i < HD * HD; i += 256) Ws[i] = W[i];

    int rowBase = blockIdx.x * GROWS;
    // stage input tile with fused bias/relu
    for (int i = tid; i < GROWS * HD; i += 256) {
        int r = rowBase + (i >> 6);
        int k = i & 63;
        float v = 0.0f;
        if (r < n) {
            v = in[r * HD + k];
            if (b_prev) v += b_prev[k];
            if (relu_prev) v = fmaxf(v, 0.0f);
        }
        Hs[i] = v;
    }
    __syncthreads();

    int c = tid & 63;
    int rsub = tid >> 6;  // 0..3
    #pragma unroll
    for (int r0 = 0; r0 < GROWS; r0 += 4) {
        int r = rowBase + r0 + rsub;
        if (r < n) {
            float acc = 0.0f;
            #pragma unroll
            for (int k = 0; k < HD; ++k)
                acc += Hs[(r0 + rsub) * HD + k] * Ws[k * HD + c];
            out[r * HD + c] = acc;
        }
    }
}

// ---------------- self-loop init: agg = dis^2 * hw ----------------
__global__ void init_agg_k(const float* __restrict__ hw, const float* __restrict__ dis,
                           float* __restrict__ agg, int n)
{
    int gid = blockIdx.x * blockDim.x + threadIdx.x;
    if (gid < n * HD) {
        int node = gid >> 6;
        float d = dis[node];
        agg[gid] = d * d * hw[gid];
    }
}

// ---------------- edge scatter-add: one wave per edge (64 channels) ----------------
__global__ void edge_agg_k(const float* __restrict__ hw, const float* __restrict__ dis,
                           const int* __restrict__ src, const int* __restrict__ dst,
                           float* __restrict__ agg, int E)
{
    int gid = blockIdx.x * blockDim.x + threadIdx.x;
    int e = gid >> 6;
    int c = gid & 63;
    if (e < E) {
        int s = src[e];
        int d = dst[e];
        float nrm = dis[s] * dis[d];
        atomicAdd(&agg[d * HD + c], hw[s * HD + c] * nrm);
    }
}

// ---------------- pooling (sum) with fused b3 ----------------
__global__ void pool_k(const float* __restrict__ h, const float* __restrict__ b3,
                       const int* __restrict__ batch, float* __restrict__ pooled, int n)
{
    int gid = blockIdx.x * blockDim.x + threadIdx.x;
    if (gid < n * HD) {
        int node = gid >> 6;
        int c = gid & 63;
        float v = h[gid] + b3[c];
        atomicAdd(&pooled[batch[node] * HD + c], v);
    }
}

// counts via binary search over sorted batch array
__global__ void counts_k(const int* __restrict__ batch, float* __restrict__ counts, int n, int G)
{
    int g = threadIdx.x;
    if (g < G) {
        // lower bound of g
        int lo = 0, hi = n;
        while (lo < hi) { int m = (lo + hi) >> 1; if (batch[m] < g) lo = m + 1; else hi = m; }
        int start = lo;
        lo = 0; hi = n;
        while (lo < hi) { int m = (lo + hi) >> 1; if (batch[m] < g + 1) lo = m + 1; else hi = m; }
        counts[g] = (float)(lo - start);
    }
}

// ---------------- final linear: out[g,o] = (pooled[g,:]/cnt[g]) @ Wl + bl ----------------
__global__ void final_k(const float* __restrict__ pooled, const float* __restrict__ counts,
                        const float* __restrict__ Wl, const float* __restrict__ bl,
                        float* __restrict__ out, int G, int O)
{
    int gid = blockIdx.x * blockDim.x + threadIdx.x;
    if (gid < G * O) {
        int g = gid / O;
        int o = gid % O;
        float inv = 1.0f / counts[g];
        float acc = 0.0f;
        #pragma unroll
        for (int k = 0; k < HD; ++k)
            acc += pooled[g * HD + k] * inv * Wl[k * O + o];
        out[gid] = acc + bl[o];
    }
}

extern "C" void kernel_launch(void* const* d_in, const int* in_sizes, int n_in,
                              void* d_out, int out_size, void* d_ws, size_t ws_size,
                              hipStream_t stream)
{
    const float* x    = (const float*)d_in[0];
    const int*   ei   = (const int*)d_in[1];
    const int*   batch= (const int*)d_in[2];
    const float* W1   = (const float*)d_in[3];
    const float* b1   = (const float*)d_in[4];
    const float* W2   = (const float*)d_in[5];
    const float* b2   = (const float*)d_in[6];
    const float* W3   = (const float*)d_in[7];
    const float* b3   = (const float*)d_in[8];
    const float* Wl   = (const float*)d_in[9];
    const float* bl   = (const float*)d_in[10];
    float* out = (float*)d_out;

    const int N = in_sizes[0] / HD;
    const int E = in_sizes[1] / 2;
    const int O = in_sizes[10];
    const int G = out_size / O;

    const int* src = ei;        // edge_index[0]
    const int* dst = ei + E;    // edge_index[1]

    // workspace layout (floats)
    float* ws = (float*)d_ws;
    float* dis    = ws;                         // N
    float* bufA   = dis + ((N + 63) & ~63);     // N*HD
    float* bufB   = bufA + (size_t)N * HD;      // N*HD
    float* pooled = bufB + (size_t)N * HD;      // G*HD
    float* counts = pooled + (size_t)G * HD;    // G

    const int TB = 256;
    int nb_node  = (N + TB - 1) / TB;
    int nb_elem  = (N * HD + TB - 1) / TB;
    int nb_edge  = (E + TB - 1) / TB;
    int nb_edgeC = ((E * HD) + TB - 1) / TB;    // E*64 = 51.2M threads
    int nb_gemm  = (N + GROWS - 1) / GROWS;

    // --- degree / dis ---
    init_deg_k<<<nb_node, TB, 0, stream>>>(dis, N);
    deg_edges_k<<<nb_edge, TB, 0, stream>>>(dst, dis, E);
    finalize_dis_k<<<nb_node, TB, 0, stream>>>(dis, N);

    // --- layer 1: h = x ---
    gemm64_k<<<nb_gemm, TB, 0, stream>>>(x, nullptr, 0, W1, bufA, N);
    init_agg_k<<<nb_elem, TB, 0, stream>>>(bufA, dis, bufB, N);
    edge_agg_k<<<nb_edgeC, TB, 0, stream>>>(bufA, dis, src, dst, bufB, E);

    // --- layer 2: input = relu(bufB + b1) fused into gemm ---
    gemm64_k<<<nb_gemm, TB, 0, stream>>>(bufB, b1, 1, W2, bufA, N);
    init_agg_k<<<nb_elem, TB, 0, stream>>>(bufA, dis, bufB, N);
    edge_agg_k<<<nb_edgeC, TB, 0, stream>>>(bufA, dis, src, dst, bufB, E);

    // --- layer 3: input = relu(bufB + b2) fused into gemm ---
    gemm64_k<<<nb_gemm, TB, 0, stream>>>(bufB, b2, 1, W3, bufA, N);
    init_agg_k<<<nb_elem, TB, 0, stream>>>(bufA, dis, bufB, N);
    edge_agg_k<<<nb_edgeC, TB, 0, stream>>>(bufA, dis, src, dst, bufB, E);

    // --- pooling (b3 fused) ---
    hipMemsetAsync(pooled, 0, (size_t)G * HD * sizeof(float), stream);
    pool_k<<<nb_elem, TB, 0, stream>>>(bufB, b3, batch, pooled, N);
    counts_k<<<1, 64, 0, stream>>>(batch, counts, N, G);

    // --- final linear ---
    int nb_fin = (G * O + TB - 1) / TB;
    final_k<<<nb_fin, TB, 0, stream>>>(pooled, counts, Wl, bl, out, G, O);
}

// Round 2
// 590.278 us; speedup vs baseline: 1.3962x; 1.3962x over previous
//
#include <hip/hip_runtime.h>

#define HD 64   // hidden/feature dim (D == H == 64)

// ---------------- CSR build: count, scan, fill ----------------

__global__ void count_deg_k(const int* __restrict__ dst, int* __restrict__ deg, int E) {
    int e = blockIdx.x * blockDim.x + threadIdx.x;
    if (e < E) atomicAdd(&deg[dst[e]], 1);
}

// Single-block exclusive scan over deg[0..n); also emits cursor copy and
// dis[i] = rsqrt(1 + deg[i]) (the +1 is the self-loop).
__global__ __launch_bounds__(1024) void scan_k(const int* __restrict__ deg,
    int* __restrict__ offsets, int* __restrict__ cursor,
    float* __restrict__ dis, int n)
{
    __shared__ int sums[1024];
    int t = threadIdx.x;
    int chunk = (n + 1023) >> 10;
    int beg = t * chunk;
    int end = min(beg + chunk, n);
    int s = 0;
    for (int i = beg; i < end; ++i) s += deg[i];
    sums[t] = s;
    __syncthreads();
    for (int off = 1; off < 1024; off <<= 1) {
        int v = (t >= off) ? sums[t - off] : 0;
        __syncthreads();
        sums[t] += v;
        __syncthreads();
    }
    int running = sums[t] - s;  // exclusive prefix
    for (int i = beg; i < end; ++i) {
        int d = deg[i];
        offsets[i] = running;
        cursor[i]  = running;
        dis[i] = rsqrtf(1.0f + (float)d);
        running += d;
    }
    if (t == 1023) offsets[n] = sums[1023];
}

__global__ void fill_csr_k(const int* __restrict__ src, const int* __restrict__ dst,
    int* __restrict__ cursor, int* __restrict__ csr_src, int E)
{
    int e = blockIdx.x * blockDim.x + threadIdx.x;
    if (e < E) {
        int p = atomicAdd(&cursor[dst[e]], 1);
        csr_src[p] = src[e];
    }
}

// ---------------- 64x64 GEMM: out[n,64] = act(in + b_prev) @ W ----------------
#define GROWS 16
__global__ __launch_bounds__(256) void gemm64_k(
    const float* __restrict__ in, const float* __restrict__ b_prev, int relu_prev,
    const float* __restrict__ W, float* __restrict__ out, int n)
{
    __shared__ float Ws[HD * HD];     // 16 KB
    __shared__ float Hs[GROWS * HD];  // 4 KB
    int tid = threadIdx.x;
    for (int i = tid; i < HD * HD; i += 256) Ws[i] = W[i];

    int rowBase = blockIdx.x * GROWS;
    for (int i = tid; i < GROWS * HD; i += 256) {
        int r = rowBase + (i >> 6);
        int k = i & 63;
        float v = 0.0f;
        if (r < n) {
            v = in[r * HD + k];
            if (b_prev) v += b_prev[k];
            if (relu_prev) v = fmaxf(v, 0.0f);
        }
        Hs[i] = v;
    }
    __syncthreads();

    int c = tid & 63;
    int rsub = tid >> 6;  // 0..3
    #pragma unroll
    for (int r0 = 0; r0 < GROWS; r0 += 4) {
        int r = rowBase + r0 + rsub;
        if (r < n) {
            float acc = 0.0f;
            #pragma unroll
            for (int k = 0; k < HD; ++k)
                acc += Hs[(r0 + rsub) * HD + k] * Ws[k * HD + c];
            out[r * HD + c] = acc;
        }
    }
}

// ---------------- CSR gather-aggregate: one wave per dst node ----------------
// agg[n,c] = dis[n]^2 * hw[n,c] + sum_{s in in(n)} dis[n]*dis[s]*hw[s,c]
__global__ __launch_bounds__(256) void agg_csr_k(const float* __restrict__ hw,
    const float* __restrict__ dis, const int* __restrict__ offsets,
    const int* __restrict__ csr_src, float* __restrict__ agg, int n)
{
    int wid  = (blockIdx.x * blockDim.x + threadIdx.x) >> 6;
    int lane = threadIdx.x & 63;
    if (wid >= n) return;
    float dn  = dis[wid];
    float acc = dn * dn * hw[(size_t)wid * HD + lane];
    int beg = offsets[wid], end = offsets[wid + 1];
    int j = beg;
    for (; j + 2 <= end; j += 2) {
        int s0 = __builtin_amdgcn_readfirstlane(csr_src[j]);
        int s1 = __builtin_amdgcn_readfirstlane(csr_src[j + 1]);
        float h0 = hw[(size_t)s0 * HD + lane];
        float h1 = hw[(size_t)s1 * HD + lane];
        acc += dn * dis[s0] * h0;
        acc += dn * dis[s1] * h1;
    }
    if (j < end) {
        int s0 = __builtin_amdgcn_readfirstlane(csr_src[j]);
        acc += dn * dis[s0] * hw[(size_t)s0 * HD + lane];
    }
    agg[(size_t)wid * HD + lane] = acc;
}

// ---------------- graph segment starts (batch is sorted) ----------------
__global__ void gstart_k(const int* __restrict__ batch, int* __restrict__ gstart, int n, int G)
{
    int g = blockIdx.x * blockDim.x + threadIdx.x;
    if (g > G) return;
    if (g == G) { gstart[g] = n; return; }
    int lo = 0, hi = n;
    while (lo < hi) { int m = (lo + hi) >> 1; if (batch[m] < g) lo = m + 1; else hi = m; }
    gstart[g] = lo;
}

// ---------------- fused mean-pool (+b3) and final linear ----------------
__global__ __launch_bounds__(256) void pool_final_k(const float* __restrict__ h,
    const float* __restrict__ b3, const int* __restrict__ gstart,
    const float* __restrict__ Wl, const float* __restrict__ bl,
    float* __restrict__ out, int O)
{
    __shared__ float ps[4][HD];
    __shared__ float pooled[HD];
    int g = blockIdx.x;
    int t = threadIdx.x;
    int lane = t & 63;
    int w = t >> 6;  // 0..3
    int s = gstart[g], e = gstart[g + 1];
    float sum = 0.0f;
    for (int i = s + w; i < e; i += 4) sum += h[(size_t)i * HD + lane];
    ps[w][lane] = sum;
    __syncthreads();
    if (t < HD) {
        float cnt = (float)(e - s);
        pooled[t] = (ps[0][t] + ps[1][t] + ps[2][t] + ps[3][t]) / cnt + b3[t];
    }
    __syncthreads();
    if (t < O) {
        float acc = bl[t];
        #pragma unroll
        for (int k = 0; k < HD; ++k) acc += pooled[k] * Wl[k * O + t];
        out[g * O + t] = acc;
    }
}

extern "C" void kernel_launch(void* const* d_in, const int* in_sizes, int n_in,
                              void* d_out, int out_size, void* d_ws, size_t ws_size,
                              hipStream_t stream)
{
    const float* x    = (const float*)d_in[0];
    const int*   ei   = (const int*)d_in[1];
    const int*   batch= (const int*)d_in[2];
    const float* W1   = (const float*)d_in[3];
    const float* b1   = (const float*)d_in[4];
    const float* W2   = (const float*)d_in[5];
    const float* b2   = (const float*)d_in[6];
    const float* W3   = (const float*)d_in[7];
    const float* b3   = (const float*)d_in[8];
    const float* Wl   = (const float*)d_in[9];
    const float* bl   = (const float*)d_in[10];
    float* out = (float*)d_out;

    const int N = in_sizes[0] / HD;
    const int E = in_sizes[1] / 2;
    const int O = in_sizes[10];
    const int G = out_size / O;

    const int* src = ei;        // edge_index[0]
    const int* dst = ei + E;    // edge_index[1]

    // ---- workspace layout (256 B aligned chunks) ----
    char* p = (char*)d_ws;
    auto take = [&](size_t bytes) { char* r = p; p += (bytes + 255) & ~(size_t)255; return r; };
    int*   deg     = (int*)  take((size_t)N * 4);
    int*   offsets = (int*)  take((size_t)(N + 1) * 4);
    int*   cursor  = (int*)  take((size_t)N * 4);
    float* dis     = (float*)take((size_t)N * 4);
    int*   csr_src = (int*)  take((size_t)E * 4);
    int*   gstart  = (int*)  take((size_t)(G + 1) * 4);
    float* bufA    = (float*)take((size_t)N * HD * 4);
    float* bufB    = (float*)take((size_t)N * HD * 4);

    const int TB = 256;
    int nb_edge = (E + TB - 1) / TB;
    int nb_gemm = (N + GROWS - 1) / GROWS;
    int nb_agg  = (N * 64 + TB - 1) / TB;   // one wave per node

    // ---- CSR build ----
    hipMemsetAsync(deg, 0, (size_t)N * 4, stream);
    count_deg_k<<<nb_edge, TB, 0, stream>>>(dst, deg, E);
    scan_k<<<1, 1024, 0, stream>>>(deg, offsets, cursor, dis, N);
    fill_csr_k<<<nb_edge, TB, 0, stream>>>(src, dst, cursor, csr_src, E);
    gstart_k<<<1, 128, 0, stream>>>(batch, gstart, N, G);

    // ---- layer 1 ----
    gemm64_k<<<nb_gemm, TB, 0, stream>>>(x, nullptr, 0, W1, bufA, N);
    agg_csr_k<<<nb_agg, TB, 0, stream>>>(bufA, dis, offsets, csr_src, bufB, N);

    // ---- layer 2 (relu(prev + b1) fused into gemm load) ----
    gemm64_k<<<nb_gemm, TB, 0, stream>>>(bufB, b1, 1, W2, bufA, N);
    agg_csr_k<<<nb_agg, TB, 0, stream>>>(bufA, dis, offsets, csr_src, bufB, N);

    // ---- layer 3 ----
    gemm64_k<<<nb_gemm, TB, 0, stream>>>(bufB, b2, 1, W3, bufA, N);
    agg_csr_k<<<nb_agg, TB, 0, stream>>>(bufA, dis, offsets, csr_src, bufB, N);

    // ---- pool + final linear ----
    pool_final_k<<<G, TB, 0, stream>>>(bufB, b3, gstart, Wl, bl, out, O);
}

// Round 3
// 470.544 us; speedup vs baseline: 1.7514x; 1.2545x over previous
//
#include <hip/hip_runtime.h>

#define HD 64   // hidden/feature dim (D == H == 64)
#define SCAN_TILE 256

// ---------------- CSR build: count, 3-kernel grid scan, fill ----------------

__global__ void count_deg_k(const int* __restrict__ dst, int* __restrict__ deg, int E) {
    int e = blockIdx.x * blockDim.x + threadIdx.x;
    if (e < E) atomicAdd(&deg[dst[e]], 1);
}

// k1: per-block tile reduction -> bsum[block]
__global__ __launch_bounds__(256) void scan1_k(const int* __restrict__ deg,
                                               int* __restrict__ bsum, int n)
{
    __shared__ int s[256];
    int t = threadIdx.x;
    int i = blockIdx.x * 256 + t;
    s[t] = (i < n) ? deg[i] : 0;
    __syncthreads();
    for (int off = 128; off > 0; off >>= 1) {
        if (t < off) s[t] += s[t + off];
        __syncthreads();
    }
    if (t == 0) bsum[blockIdx.x] = s[0];
}

// k2: single block exclusive-scans bsum[0..nb)  (nb <= 1024)
__global__ __launch_bounds__(1024) void scan2_k(int* __restrict__ bsum, int nb)
{
    __shared__ int s[1024];
    int t = threadIdx.x;
    int v = (t < nb) ? bsum[t] : 0;
    s[t] = v;
    __syncthreads();
    for (int off = 1; off < 1024; off <<= 1) {
        int u = (t >= off) ? s[t - off] : 0;
        __syncthreads();
        s[t] += u;
        __syncthreads();
    }
    if (t < nb) bsum[t] = s[t] - v;  // exclusive prefix of block sums
}

// k3: per-block local scan + block offset; fused cursor copy and dis=rsqrt(1+deg)
__global__ __launch_bounds__(256) void scan3_k(const int* __restrict__ deg,
    const int* __restrict__ bsum, int* __restrict__ offsets,
    int* __restrict__ cursor, float* __restrict__ dis, int n)
{
    __shared__ int s[256];
    int t = threadIdx.x;
    int i = blockIdx.x * 256 + t;
    int d = (i < n) ? deg[i] : 0;
    s[t] = d;
    __syncthreads();
    for (int off = 1; off < 256; off <<= 1) {
        int u = (t >= off) ? s[t - off] : 0;
        __syncthreads();
        s[t] += u;
        __syncthreads();
    }
    if (i < n) {
        int excl = bsum[blockIdx.x] + s[t] - d;
        offsets[i] = excl;
        cursor[i]  = excl;
        dis[i] = rsqrtf(1.0f + (float)d);
        if (i == n - 1) offsets[n] = excl + d;
    }
}

__global__ void fill_csr_k(const int* __restrict__ src, const int* __restrict__ dst,
    int* __restrict__ cursor, int* __restrict__ csr_src, int E)
{
    int e = blockIdx.x * blockDim.x + threadIdx.x;
    if (e < E) {
        int p = atomicAdd(&cursor[dst[e]], 1);
        csr_src[p] = src[e];
    }
}

// ---------------- 64x64 GEMM: out[n,64] = act(in + b_prev) @ W ----------------
#define GROWS 16
__global__ __launch_bounds__(256) void gemm64_k(
    const float* __restrict__ in, const float* __restrict__ b_prev, int relu_prev,
    const float* __restrict__ W, float* __restrict__ out, int n)
{
    __shared__ float Ws[HD * HD];     // 16 KB
    __shared__ float Hs[GROWS * HD];  // 4 KB
    int tid = threadIdx.x;
    for (int i = tid; i < HD * HD; i += 256) Ws[i] = W[i];

    int rowBase = blockIdx.x * GROWS;
    for (int i = tid; i < GROWS * HD; i += 256) {
        int r = rowBase + (i >> 6);
        int k = i & 63;
        float v = 0.0f;
        if (r < n) {
            v = in[r * HD + k];
            if (b_prev) v += b_prev[k];
            if (relu_prev) v = fmaxf(v, 0.0f);
        }
        Hs[i] = v;
    }
    __syncthreads();

    int c = tid & 63;
    int rsub = tid >> 6;  // 0..3
    #pragma unroll
    for (int r0 = 0; r0 < GROWS; r0 += 4) {
        int r = rowBase + r0 + rsub;
        if (r < n) {
            float acc = 0.0f;
            #pragma unroll
            for (int k = 0; k < HD; ++k)
                acc += Hs[(r0 + rsub) * HD + k] * Ws[k * HD + c];
            out[r * HD + c] = acc;
        }
    }
}

// ---------------- CSR gather-aggregate: one wave per dst node ----------------
// agg[n,c] = dis[n]^2 * hw[n,c] + sum_{s in in(n)} dis[n]*dis[s]*hw[s,c]
__global__ __launch_bounds__(256) void agg_csr_k(const float* __restrict__ hw,
    const float* __restrict__ dis, const int* __restrict__ offsets,
    const int* __restrict__ csr_src, float* __restrict__ agg, int n)
{
    int wid  = (blockIdx.x * blockDim.x + threadIdx.x) >> 6;
    int lane = threadIdx.x & 63;
    if (wid >= n) return;
    float dn  = dis[wid];
    float acc = dn * dn * hw[(size_t)wid * HD + lane];
    int beg = offsets[wid], end = offsets[wid + 1];
    int j = beg;
    for (; j + 2 <= end; j += 2) {
        int s0 = __builtin_amdgcn_readfirstlane(csr_src[j]);
        int s1 = __builtin_amdgcn_readfirstlane(csr_src[j + 1]);
        float h0 = hw[(size_t)s0 * HD + lane];
        float h1 = hw[(size_t)s1 * HD + lane];
        acc += dn * dis[s0] * h0;
        acc += dn * dis[s1] * h1;
    }
    if (j < end) {
        int s0 = __builtin_amdgcn_readfirstlane(csr_src[j]);
        acc += dn * dis[s0] * hw[(size_t)s0 * HD + lane];
    }
    agg[(size_t)wid * HD + lane] = acc;
}

// ---------------- graph segment starts (batch is sorted) ----------------
__global__ void gstart_k(const int* __restrict__ batch, int* __restrict__ gstart, int n, int G)
{
    int g = blockIdx.x * blockDim.x + threadIdx.x;
    if (g > G) return;
    if (g == G) { gstart[g] = n; return; }
    int lo = 0, hi = n;
    while (lo < hi) { int m = (lo + hi) >> 1; if (batch[m] < g) lo = m + 1; else hi = m; }
    gstart[g] = lo;
}

// ---------------- fused mean-pool (+b3) and final linear ----------------
__global__ __launch_bounds__(256) void pool_final_k(const float* __restrict__ h,
    const float* __restrict__ b3, const int* __restrict__ gstart,
    const float* __restrict__ Wl, const float* __restrict__ bl,
    float* __restrict__ out, int O)
{
    __shared__ float ps[4][HD];
    __shared__ float pooled[HD];
    int g = blockIdx.x;
    int t = threadIdx.x;
    int lane = t & 63;
    int w = t >> 6;  // 0..3
    int s = gstart[g], e = gstart[g + 1];
    float sum = 0.0f;
    for (int i = s + w; i < e; i += 4) sum += h[(size_t)i * HD + lane];
    ps[w][lane] = sum;
    __syncthreads();
    if (t < HD) {
        float cnt = (float)(e - s);
        pooled[t] = (ps[0][t] + ps[1][t] + ps[2][t] + ps[3][t]) / cnt + b3[t];
    }
    __syncthreads();
    if (t < O) {
        float acc = bl[t];
        #pragma unroll
        for (int k = 0; k < HD; ++k) acc += pooled[k] * Wl[k * O + t];
        out[g * O + t] = acc;
    }
}

extern "C" void kernel_launch(void* const* d_in, const int* in_sizes, int n_in,
                              void* d_out, int out_size, void* d_ws, size_t ws_size,
                              hipStream_t stream)
{
    const float* x    = (const float*)d_in[0];
    const int*   ei   = (const int*)d_in[1];
    const int*   batch= (const int*)d_in[2];
    const float* W1   = (const float*)d_in[3];
    const float* b1   = (const float*)d_in[4];
    const float* W2   = (const float*)d_in[5];
    const float* b2   = (const float*)d_in[6];
    const float* W3   = (const float*)d_in[7];
    const float* b3   = (const float*)d_in[8];
    const float* Wl   = (const float*)d_in[9];
    const float* bl   = (const float*)d_in[10];
    float* out = (float*)d_out;

    const int N = in_sizes[0] / HD;
    const int E = in_sizes[1] / 2;
    const int O = in_sizes[10];
    const int G = out_size / O;

    const int* src = ei;        // edge_index[0]
    const int* dst = ei + E;    // edge_index[1]

    // ---- workspace layout (256 B aligned chunks) ----
    char* p = (char*)d_ws;
    auto take = [&](size_t bytes) { char* r = p; p += (bytes + 255) & ~(size_t)255; return r; };
    int*   deg     = (int*)  take((size_t)N * 4);
    int*   offsets = (int*)  take((size_t)(N + 1) * 4);
    int*   cursor  = (int*)  take((size_t)N * 4);
    float* dis     = (float*)take((size_t)N * 4);
    int*   csr_src = (int*)  take((size_t)E * 4);
    int*   gstart  = (int*)  take((size_t)(G + 1) * 4);
    int*   bsum    = (int*)  take((size_t)1024 * 4);
    float* bufA    = (float*)take((size_t)N * HD * 4);
    float* bufB    = (float*)take((size_t)N * HD * 4);

    const int TB = 256;
    int nb_edge = (E + TB - 1) / TB;
    int nb_gemm = (N + GROWS - 1) / GROWS;
    int nb_agg  = (N * 64 + TB - 1) / TB;   // one wave per node
    int nb_scan = (N + SCAN_TILE - 1) / SCAN_TILE;   // 196 blocks @ N=50k

    // ---- CSR build ----
    hipMemsetAsync(deg, 0, (size_t)N * 4, stream);
    count_deg_k<<<nb_edge, TB, 0, stream>>>(dst, deg, E);
    scan1_k<<<nb_scan, 256, 0, stream>>>(deg, bsum, N);
    scan2_k<<<1, 1024, 0, stream>>>(bsum, nb_scan);
    scan3_k<<<nb_scan, 256, 0, stream>>>(deg, bsum, offsets, cursor, dis, N);
    fill_csr_k<<<nb_edge, TB, 0, stream>>>(src, dst, cursor, csr_src, E);
    gstart_k<<<1, 128, 0, stream>>>(batch, gstart, N, G);

    // ---- layer 1 ----
    gemm64_k<<<nb_gemm, TB, 0, stream>>>(x, nullptr, 0, W1, bufA, N);
    agg_csr_k<<<nb_agg, TB, 0, stream>>>(bufA, dis, offsets, csr_src, bufB, N);

    // ---- layer 2 (relu(prev + b1) fused into gemm load) ----
    gemm64_k<<<nb_gemm, TB, 0, stream>>>(bufB, b1, 1, W2, bufA, N);
    agg_csr_k<<<nb_agg, TB, 0, stream>>>(bufA, dis, offsets, csr_src, bufB, N);

    // ---- layer 3 ----
    gemm64_k<<<nb_gemm, TB, 0, stream>>>(bufB, b2, 1, W3, bufA, N);
    agg_csr_k<<<nb_agg, TB, 0, stream>>>(bufA, dis, offsets, csr_src, bufB, N);

    // ---- pool + final linear ----
    pool_final_k<<<G, TB, 0, stream>>>(bufB, b3, gstart, Wl, bl, out, O);
}

// Round 4
// 408.009 us; speedup vs baseline: 2.0199x; 1.1533x over previous
//
#include <hip/hip_runtime.h>

#define HD 64   // hidden/feature dim (D == H == 64)
#define SCAN_TILE 256
#define PSUB 16  // sub-blocks per graph for pooling stage 1

// ---------------- CSR build: count, 3-kernel grid scan, fill ----------------

__global__ void count_deg_k(const int* __restrict__ dst, int* __restrict__ deg, int E) {
    int e = blockIdx.x * blockDim.x + threadIdx.x;
    if (e < E) atomicAdd(&deg[dst[e]], 1);
}

// k1: per-block tile reduction -> bsum[block]
__global__ __launch_bounds__(256) void scan1_k(const int* __restrict__ deg,
                                               int* __restrict__ bsum, int n)
{
    __shared__ int s[256];
    int t = threadIdx.x;
    int i = blockIdx.x * 256 + t;
    s[t] = (i < n) ? deg[i] : 0;
    __syncthreads();
    for (int off = 128; off > 0; off >>= 1) {
        if (t < off) s[t] += s[t + off];
        __syncthreads();
    }
    if (t == 0) bsum[blockIdx.x] = s[0];
}

// k2: single block exclusive-scans bsum[0..nb)  (nb <= 1024)
__global__ __launch_bounds__(1024) void scan2_k(int* __restrict__ bsum, int nb)
{
    __shared__ int s[1024];
    int t = threadIdx.x;
    int v = (t < nb) ? bsum[t] : 0;
    s[t] = v;
    __syncthreads();
    for (int off = 1; off < 1024; off <<= 1) {
        int u = (t >= off) ? s[t - off] : 0;
        __syncthreads();
        s[t] += u;
        __syncthreads();
    }
    if (t < nb) bsum[t] = s[t] - v;  // exclusive prefix of block sums
}

// k3: per-block local scan + block offset; fused cursor copy and dis=rsqrt(1+deg)
__global__ __launch_bounds__(256) void scan3_k(const int* __restrict__ deg,
    const int* __restrict__ bsum, int* __restrict__ offsets,
    int* __restrict__ cursor, float* __restrict__ dis, int n)
{
    __shared__ int s[256];
    int t = threadIdx.x;
    int i = blockIdx.x * 256 + t;
    int d = (i < n) ? deg[i] : 0;
    s[t] = d;
    __syncthreads();
    for (int off = 1; off < 256; off <<= 1) {
        int u = (t >= off) ? s[t - off] : 0;
        __syncthreads();
        s[t] += u;
        __syncthreads();
    }
    if (i < n) {
        int excl = bsum[blockIdx.x] + s[t] - d;
        offsets[i] = excl;
        cursor[i]  = excl;
        dis[i] = rsqrtf(1.0f + (float)d);
        if (i == n - 1) offsets[n] = excl + d;
    }
}

__global__ void fill_csr_k(const int* __restrict__ src, const int* __restrict__ dst,
    int* __restrict__ cursor, int* __restrict__ csr_src, int E)
{
    int e = blockIdx.x * blockDim.x + threadIdx.x;
    if (e < E) {
        int p = atomicAdd(&cursor[dst[e]], 1);
        csr_src[p] = src[e];
    }
}

// ---------------- 64x64 GEMM: out[n,64] = act(in + b_prev) @ W ----------------
#define GROWS 16
__global__ __launch_bounds__(256) void gemm64_k(
    const float* __restrict__ in, const float* __restrict__ b_prev, int relu_prev,
    const float* __restrict__ W, float* __restrict__ out, int n)
{
    __shared__ float Ws[HD * HD];     // 16 KB
    __shared__ float Hs[GROWS * HD];  // 4 KB
    int tid = threadIdx.x;
    for (int i = tid; i < HD * HD; i += 256) Ws[i] = W[i];

    int rowBase = blockIdx.x * GROWS;
    for (int i = tid; i < GROWS * HD; i += 256) {
        int r = rowBase + (i >> 6);
        int k = i & 63;
        float v = 0.0f;
        if (r < n) {
            v = in[r * HD + k];
            if (b_prev) v += b_prev[k];
            if (relu_prev) v = fmaxf(v, 0.0f);
        }
        Hs[i] = v;
    }
    __syncthreads();

    int c = tid & 63;
    int rsub = tid >> 6;  // 0..3
    #pragma unroll
    for (int r0 = 0; r0 < GROWS; r0 += 4) {
        int r = rowBase + r0 + rsub;
        if (r < n) {
            float acc = 0.0f;
            #pragma unroll
            for (int k = 0; k < HD; ++k)
                acc += Hs[(r0 + rsub) * HD + k] * Ws[k * HD + c];
            out[r * HD + c] = acc;
        }
    }
}

// ---------------- CSR gather-aggregate: one wave per dst node ----------------
// agg[n,c] = dis[n]^2 * hw[n,c] + sum_{s in in(n)} dis[n]*dis[s]*hw[s,c]
__global__ __launch_bounds__(256) void agg_csr_k(const float* __restrict__ hw,
    const float* __restrict__ dis, const int* __restrict__ offsets,
    const int* __restrict__ csr_src, float* __restrict__ agg, int n)
{
    int wid  = (blockIdx.x * blockDim.x + threadIdx.x) >> 6;
    int lane = threadIdx.x & 63;
    if (wid >= n) return;
    float dn  = dis[wid];
    float acc = dn * dn * hw[(size_t)wid * HD + lane];
    int beg = offsets[wid], end = offsets[wid + 1];
    int j = beg;
    for (; j + 2 <= end; j += 2) {
        int s0 = __builtin_amdgcn_readfirstlane(csr_src[j]);
        int s1 = __builtin_amdgcn_readfirstlane(csr_src[j + 1]);
        float h0 = hw[(size_t)s0 * HD + lane];
        float h1 = hw[(size_t)s1 * HD + lane];
        acc += dn * dis[s0] * h0;
        acc += dn * dis[s1] * h1;
    }
    if (j < end) {
        int s0 = __builtin_amdgcn_readfirstlane(csr_src[j]);
        acc += dn * dis[s0] * hw[(size_t)s0 * HD + lane];
    }
    agg[(size_t)wid * HD + lane] = acc;
}

// ---------------- graph segment starts (batch is sorted) ----------------
__global__ void gstart_k(const int* __restrict__ batch, int* __restrict__ gstart, int n, int G)
{
    int g = blockIdx.x * blockDim.x + threadIdx.x;
    if (g > G) return;
    if (g == G) { gstart[g] = n; return; }
    int lo = 0, hi = n;
    while (lo < hi) { int m = (lo + hi) >> 1; if (batch[m] < g) lo = m + 1; else hi = m; }
    gstart[g] = lo;
}

// ---------------- pooling stage 1: per-(graph, sub-chunk) partial sums ----------------
__global__ __launch_bounds__(256) void pool1_k(const float* __restrict__ h,
    const int* __restrict__ gstart, float* __restrict__ partial)
{
    __shared__ float ps[4][HD];
    int g = blockIdx.x;
    int s = blockIdx.y;
    int t = threadIdx.x;
    int lane = t & 63;
    int w = t >> 6;  // 0..3
    int beg = gstart[g], end = gstart[g + 1];
    int len = end - beg;
    int c0 = beg + (int)(((long long)len * s) / PSUB);
    int c1 = beg + (int)(((long long)len * (s + 1)) / PSUB);
    float sum = 0.0f;
    for (int i = c0 + w; i < c1; i += 4) sum += h[(size_t)i * HD + lane];
    ps[w][lane] = sum;
    __syncthreads();
    if (t < HD)
        partial[((size_t)g * PSUB + s) * HD + t] = ps[0][t] + ps[1][t] + ps[2][t] + ps[3][t];
}

// ---------------- pooling stage 2: reduce partials, mean + b3, final linear ----------------
__global__ __launch_bounds__(64) void pool2_k(const float* __restrict__ partial,
    const int* __restrict__ gstart, const float* __restrict__ b3,
    const float* __restrict__ Wl, const float* __restrict__ bl,
    float* __restrict__ out, int O)
{
    __shared__ float pooled[HD];
    int g = blockIdx.x;
    int t = threadIdx.x;  // 0..63 = channel
    float sum = 0.0f;
    #pragma unroll
    for (int s = 0; s < PSUB; ++s)
        sum += partial[((size_t)g * PSUB + s) * HD + t];
    float cnt = (float)(gstart[g + 1] - gstart[g]);
    pooled[t] = sum / cnt + b3[t];
    __syncthreads();
    if (t < O) {
        float acc = bl[t];
        #pragma unroll
        for (int k = 0; k < HD; ++k) acc += pooled[k] * Wl[k * O + t];
        out[g * O + t] = acc;
    }
}

extern "C" void kernel_launch(void* const* d_in, const int* in_sizes, int n_in,
                              void* d_out, int out_size, void* d_ws, size_t ws_size,
                              hipStream_t stream)
{
    const float* x    = (const float*)d_in[0];
    const int*   ei   = (const int*)d_in[1];
    const int*   batch= (const int*)d_in[2];
    const float* W1   = (const float*)d_in[3];
    const float* b1   = (const float*)d_in[4];
    const float* W2   = (const float*)d_in[5];
    const float* b2   = (const float*)d_in[6];
    const float* W3   = (const float*)d_in[7];
    const float* b3   = (const float*)d_in[8];
    const float* Wl   = (const float*)d_in[9];
    const float* bl   = (const float*)d_in[10];
    float* out = (float*)d_out;

    const int N = in_sizes[0] / HD;
    const int E = in_sizes[1] / 2;
    const int O = in_sizes[10];
    const int G = out_size / O;

    const int* src = ei;        // edge_index[0]
    const int* dst = ei + E;    // edge_index[1]

    // ---- workspace layout (256 B aligned chunks) ----
    char* p = (char*)d_ws;
    auto take = [&](size_t bytes) { char* r = p; p += (bytes + 255) & ~(size_t)255; return r; };
    int*   deg     = (int*)  take((size_t)N * 4);
    int*   offsets = (int*)  take((size_t)(N + 1) * 4);
    int*   cursor  = (int*)  take((size_t)N * 4);
    float* dis     = (float*)take((size_t)N * 4);
    int*   csr_src = (int*)  take((size_t)E * 4);
    int*   gstart  = (int*)  take((size_t)(G + 1) * 4);
    int*   bsum    = (int*)  take((size_t)1024 * 4);
    float* partial = (float*)take((size_t)G * PSUB * HD * 4);
    float* bufA    = (float*)take((size_t)N * HD * 4);
    float* bufB    = (float*)take((size_t)N * HD * 4);

    const int TB = 256;
    int nb_edge = (E + TB - 1) / TB;
    int nb_gemm = (N + GROWS - 1) / GROWS;
    int nb_agg  = (N * 64 + TB - 1) / TB;   // one wave per node
    int nb_scan = (N + SCAN_TILE - 1) / SCAN_TILE;   // 196 blocks @ N=50k

    // ---- CSR build ----
    hipMemsetAsync(deg, 0, (size_t)N * 4, stream);
    count_deg_k<<<nb_edge, TB, 0, stream>>>(dst, deg, E);
    scan1_k<<<nb_scan, 256, 0, stream>>>(deg, bsum, N);
    scan2_k<<<1, 1024, 0, stream>>>(bsum, nb_scan);
    scan3_k<<<nb_scan, 256, 0, stream>>>(deg, bsum, offsets, cursor, dis, N);
    fill_csr_k<<<nb_edge, TB, 0, stream>>>(src, dst, cursor, csr_src, E);
    gstart_k<<<1, 128, 0, stream>>>(batch, gstart, N, G);

    // ---- layer 1 ----
    gemm64_k<<<nb_gemm, TB, 0, stream>>>(x, nullptr, 0, W1, bufA, N);
    agg_csr_k<<<nb_agg, TB, 0, stream>>>(bufA, dis, offsets, csr_src, bufB, N);

    // ---- layer 2 (relu(prev + b1) fused into gemm load) ----
    gemm64_k<<<nb_gemm, TB, 0, stream>>>(bufB, b1, 1, W2, bufA, N);
    agg_csr_k<<<nb_agg, TB, 0, stream>>>(bufA, dis, offsets, csr_src, bufB, N);

    // ---- layer 3 ----
    gemm64_k<<<nb_gemm, TB, 0, stream>>>(bufB, b2, 1, W3, bufA, N);
    agg_csr_k<<<nb_agg, TB, 0, stream>>>(bufA, dis, offsets, csr_src, bufB, N);

    // ---- pool (2-stage) + final linear ----
    pool1_k<<<dim3(G, PSUB), TB, 0, stream>>>(bufB, gstart, partial);
    pool2_k<<<G, 64, 0, stream>>>(partial, gstart, b3, Wl, bl, out, O);
}

// Round 5
// 369.524 us; speedup vs baseline: 2.2303x; 1.1041x over previous
//
#include <hip/hip_runtime.h>

#define HD 64   // hidden/feature dim (D == H == 64)
#define SCAN_TILE 256
#define PSUB 16  // sub-blocks per graph for pooling stage 1

// ---- bf16 helpers (manual, RNE) ----
__device__ __forceinline__ unsigned short f2bf(float f) {
    union { float f; unsigned u; } v; v.f = f;
    unsigned r = v.u + 0x7FFF + ((v.u >> 16) & 1);
    return (unsigned short)(r >> 16);
}
__device__ __forceinline__ float bf2f(unsigned short h) {
    union { unsigned u; float f; } v; v.u = ((unsigned)h) << 16;
    return v.f;
}

// ---------------- CSR build: count, 3-kernel grid scan, fill ----------------

__global__ void count_deg_k(const int* __restrict__ dst, int* __restrict__ deg, int E) {
    int e = blockIdx.x * blockDim.x + threadIdx.x;
    if (e < E) atomicAdd(&deg[dst[e]], 1);
}

__global__ __launch_bounds__(256) void scan1_k(const int* __restrict__ deg,
                                               int* __restrict__ bsum, int n)
{
    __shared__ int s[256];
    int t = threadIdx.x;
    int i = blockIdx.x * 256 + t;
    s[t] = (i < n) ? deg[i] : 0;
    __syncthreads();
    for (int off = 128; off > 0; off >>= 1) {
        if (t < off) s[t] += s[t + off];
        __syncthreads();
    }
    if (t == 0) bsum[blockIdx.x] = s[0];
}

__global__ __launch_bounds__(1024) void scan2_k(int* __restrict__ bsum, int nb)
{
    __shared__ int s[1024];
    int t = threadIdx.x;
    int v = (t < nb) ? bsum[t] : 0;
    s[t] = v;
    __syncthreads();
    for (int off = 1; off < 1024; off <<= 1) {
        int u = (t >= off) ? s[t - off] : 0;
        __syncthreads();
        s[t] += u;
        __syncthreads();
    }
    if (t < nb) bsum[t] = s[t] - v;  // exclusive prefix of block sums
}

__global__ __launch_bounds__(256) void scan3_k(const int* __restrict__ deg,
    const int* __restrict__ bsum, int* __restrict__ offsets,
    int* __restrict__ cursor, float* __restrict__ dis, int n)
{
    __shared__ int s[256];
    int t = threadIdx.x;
    int i = blockIdx.x * 256 + t;
    int d = (i < n) ? deg[i] : 0;
    s[t] = d;
    __syncthreads();
    for (int off = 1; off < 256; off <<= 1) {
        int u = (t >= off) ? s[t - off] : 0;
        __syncthreads();
        s[t] += u;
        __syncthreads();
    }
    if (i < n) {
        int excl = bsum[blockIdx.x] + s[t] - d;
        offsets[i] = excl;
        cursor[i]  = excl;
        dis[i] = rsqrtf(1.0f + (float)d);
        if (i == n - 1) offsets[n] = excl + d;
    }
}

__global__ void fill_csr_k(const int* __restrict__ src, const int* __restrict__ dst,
    int* __restrict__ cursor, int* __restrict__ csr_src, int E)
{
    int e = blockIdx.x * blockDim.x + threadIdx.x;
    if (e < E) {
        int p = atomicAdd(&cursor[dst[e]], 1);
        csr_src[p] = src[e];
    }
}

// ---------------- register-tiled 64x64 GEMM, bf16 output ----------------
// out[n,64](bf16) = act(in + b_prev) @ W ; 64 rows per block, 4x4 reg tiles.
__global__ __launch_bounds__(256) void gemm64_k(
    const float* __restrict__ in, const float* __restrict__ b_prev, int relu_prev,
    const float* __restrict__ W, unsigned short* __restrict__ outb, int n)
{
    __shared__ float HsT[HD][68];   // [k][r], padded leading dim (17.4 KB)
    __shared__ float Ws[HD][HD];    // [k][c] (16 KB)
    int t = threadIdx.x;
    int rowBase = blockIdx.x * 64;

    // stage W (coalesced float4)
    for (int i = t; i < HD * HD / 4; i += 256)
        ((float4*)Ws)[i] = ((const float4*)W)[i];

    // stage input transposed, fused bias/relu. thread: r=t>>4 (+16*it), k0=(t&15)*4
    {
        int k0 = (t & 15) * 4;
        float4 bb = make_float4(0.f, 0.f, 0.f, 0.f);
        if (b_prev) bb = *(const float4*)&b_prev[k0];
        for (int it = 0; it < 4; ++it) {
            int r = (t >> 4) + it * 16;
            int row = rowBase + r;
            float4 v = make_float4(0.f, 0.f, 0.f, 0.f);
            if (row < n) {
                v = *(const float4*)&in[(size_t)row * HD + k0];
                v.x += bb.x; v.y += bb.y; v.z += bb.z; v.w += bb.w;
                if (relu_prev) {
                    v.x = fmaxf(v.x, 0.f); v.y = fmaxf(v.y, 0.f);
                    v.z = fmaxf(v.z, 0.f); v.w = fmaxf(v.w, 0.f);
                }
            }
            HsT[k0 + 0][r] = v.x;
            HsT[k0 + 1][r] = v.y;
            HsT[k0 + 2][r] = v.z;
            HsT[k0 + 3][r] = v.w;
        }
    }
    __syncthreads();

    int c4 = (t & 15) * 4;
    int r4 = (t >> 4) * 4;
    float acc[4][4];
    #pragma unroll
    for (int i = 0; i < 4; ++i)
        #pragma unroll
        for (int j = 0; j < 4; ++j) acc[i][j] = 0.f;

    #pragma unroll 8
    for (int k = 0; k < HD; ++k) {
        float4 a = *(const float4*)&HsT[k][r4];
        float4 b = *(const float4*)&Ws[k][c4];
        acc[0][0] += a.x * b.x; acc[0][1] += a.x * b.y; acc[0][2] += a.x * b.z; acc[0][3] += a.x * b.w;
        acc[1][0] += a.y * b.x; acc[1][1] += a.y * b.y; acc[1][2] += a.y * b.z; acc[1][3] += a.y * b.w;
        acc[2][0] += a.z * b.x; acc[2][1] += a.z * b.y; acc[2][2] += a.z * b.z; acc[2][3] += a.z * b.w;
        acc[3][0] += a.w * b.x; acc[3][1] += a.w * b.y; acc[3][2] += a.w * b.z; acc[3][3] += a.w * b.w;
    }

    #pragma unroll
    for (int i = 0; i < 4; ++i) {
        int row = rowBase + r4 + i;
        if (row < n) {
            ushort4 o;
            o.x = f2bf(acc[i][0]); o.y = f2bf(acc[i][1]);
            o.z = f2bf(acc[i][2]); o.w = f2bf(acc[i][3]);
            *(ushort4*)&outb[(size_t)row * HD + c4] = o;
        }
    }
}

// ---------------- CSR gather-aggregate (bf16 hw): one wave per dst node ----------------
__global__ __launch_bounds__(256) void agg_csr_k(const unsigned short* __restrict__ hwb,
    const float* __restrict__ dis, const int* __restrict__ offsets,
    const int* __restrict__ csr_src, float* __restrict__ agg, int n)
{
    int wid  = (blockIdx.x * blockDim.x + threadIdx.x) >> 6;
    int lane = threadIdx.x & 63;
    if (wid >= n) return;
    float dn  = dis[wid];
    float acc = dn * dn * bf2f(hwb[(size_t)wid * HD + lane]);
    int beg = offsets[wid], end = offsets[wid + 1];
    int j = beg;
    for (; j + 2 <= end; j += 2) {
        int s0 = __builtin_amdgcn_readfirstlane(csr_src[j]);
        int s1 = __builtin_amdgcn_readfirstlane(csr_src[j + 1]);
        float h0 = bf2f(hwb[(size_t)s0 * HD + lane]);
        float h1 = bf2f(hwb[(size_t)s1 * HD + lane]);
        acc += dn * dis[s0] * h0;
        acc += dn * dis[s1] * h1;
    }
    if (j < end) {
        int s0 = __builtin_amdgcn_readfirstlane(csr_src[j]);
        acc += dn * dis[s0] * bf2f(hwb[(size_t)s0 * HD + lane]);
    }
    agg[(size_t)wid * HD + lane] = acc;
}

// ---------------- graph segment starts (batch is sorted) ----------------
__global__ void gstart_k(const int* __restrict__ batch, int* __restrict__ gstart, int n, int G)
{
    int g = blockIdx.x * blockDim.x + threadIdx.x;
    if (g > G) return;
    if (g == G) { gstart[g] = n; return; }
    int lo = 0, hi = n;
    while (lo < hi) { int m = (lo + hi) >> 1; if (batch[m] < g) lo = m + 1; else hi = m; }
    gstart[g] = lo;
}

// ---------------- pooling stage 1: per-(graph, sub-chunk) partial sums ----------------
__global__ __launch_bounds__(256) void pool1_k(const float* __restrict__ h,
    const int* __restrict__ gstart, float* __restrict__ partial)
{
    __shared__ float ps[4][HD];
    int g = blockIdx.x;
    int s = blockIdx.y;
    int t = threadIdx.x;
    int lane = t & 63;
    int w = t >> 6;  // 0..3
    int beg = gstart[g], end = gstart[g + 1];
    int len = end - beg;
    int c0 = beg + (int)(((long long)len * s) / PSUB);
    int c1 = beg + (int)(((long long)len * (s + 1)) / PSUB);
    float sum = 0.0f;
    for (int i = c0 + w; i < c1; i += 4) sum += h[(size_t)i * HD + lane];
    ps[w][lane] = sum;
    __syncthreads();
    if (t < HD)
        partial[((size_t)g * PSUB + s) * HD + t] = ps[0][t] + ps[1][t] + ps[2][t] + ps[3][t];
}

// ---------------- pooling stage 2: reduce partials, mean + b3, final linear ----------------
__global__ __launch_bounds__(64) void pool2_k(const float* __restrict__ partial,
    const int* __restrict__ gstart, const float* __restrict__ b3,
    const float* __restrict__ Wl, const float* __restrict__ bl,
    float* __restrict__ out, int O)
{
    __shared__ float pooled[HD];
    int g = blockIdx.x;
    int t = threadIdx.x;  // 0..63 = channel
    float sum = 0.0f;
    #pragma unroll
    for (int s = 0; s < PSUB; ++s)
        sum += partial[((size_t)g * PSUB + s) * HD + t];
    float cnt = (float)(gstart[g + 1] - gstart[g]);
    pooled[t] = sum / cnt + b3[t];
    __syncthreads();
    if (t < O) {
        float acc = bl[t];
        #pragma unroll
        for (int k = 0; k < HD; ++k) acc += pooled[k] * Wl[k * O + t];
        out[g * O + t] = acc;
    }
}

extern "C" void kernel_launch(void* const* d_in, const int* in_sizes, int n_in,
                              void* d_out, int out_size, void* d_ws, size_t ws_size,
                              hipStream_t stream)
{
    const float* x    = (const float*)d_in[0];
    const int*   ei   = (const int*)d_in[1];
    const int*   batch= (const int*)d_in[2];
    const float* W1   = (const float*)d_in[3];
    const float* b1   = (const float*)d_in[4];
    const float* W2   = (const float*)d_in[5];
    const float* b2   = (const float*)d_in[6];
    const float* W3   = (const float*)d_in[7];
    const float* b3   = (const float*)d_in[8];
    const float* Wl   = (const float*)d_in[9];
    const float* bl   = (const float*)d_in[10];
    float* out = (float*)d_out;

    const int N = in_sizes[0] / HD;
    const int E = in_sizes[1] / 2;
    const int O = in_sizes[10];
    const int G = out_size / O;

    const int* src = ei;        // edge_index[0]
    const int* dst = ei + E;    // edge_index[1]

    // ---- workspace layout (256 B aligned chunks) ----
    char* p = (char*)d_ws;
    auto take = [&](size_t bytes) { char* r = p; p += (bytes + 255) & ~(size_t)255; return r; };
    int*   deg     = (int*)  take((size_t)N * 4);
    int*   offsets = (int*)  take((size_t)(N + 1) * 4);
    int*   cursor  = (int*)  take((size_t)N * 4);
    float* dis     = (float*)take((size_t)N * 4);
    int*   csr_src = (int*)  take((size_t)E * 4);
    int*   gstart  = (int*)  take((size_t)(G + 1) * 4);
    int*   bsum    = (int*)  take((size_t)1024 * 4);
    float* partial = (float*)take((size_t)G * PSUB * HD * 4);
    unsigned short* hwb = (unsigned short*)take((size_t)N * HD * 2);
    float* aggF    = (float*)take((size_t)N * HD * 4);

    const int TB = 256;
    int nb_edge = (E + TB - 1) / TB;
    int nb_gemm = (N + 63) / 64;
    int nb_agg  = (N * 64 + TB - 1) / TB;   // one wave per node
    int nb_scan = (N + SCAN_TILE - 1) / SCAN_TILE;

    // ---- CSR build ----
    hipMemsetAsync(deg, 0, (size_t)N * 4, stream);
    count_deg_k<<<nb_edge, TB, 0, stream>>>(dst, deg, E);
    scan1_k<<<nb_scan, 256, 0, stream>>>(deg, bsum, N);
    scan2_k<<<1, 1024, 0, stream>>>(bsum, nb_scan);
    scan3_k<<<nb_scan, 256, 0, stream>>>(deg, bsum, offsets, cursor, dis, N);
    fill_csr_k<<<nb_edge, TB, 0, stream>>>(src, dst, cursor, csr_src, E);
    gstart_k<<<1, 128, 0, stream>>>(batch, gstart, N, G);

    // ---- layer 1 ----
    gemm64_k<<<nb_gemm, TB, 0, stream>>>(x, nullptr, 0, W1, hwb, N);
    agg_csr_k<<<nb_agg, TB, 0, stream>>>(hwb, dis, offsets, csr_src, aggF, N);

    // ---- layer 2 (relu(prev + b1) fused into gemm load) ----
    gemm64_k<<<nb_gemm, TB, 0, stream>>>(aggF, b1, 1, W2, hwb, N);
    agg_csr_k<<<nb_agg, TB, 0, stream>>>(hwb, dis, offsets, csr_src, aggF, N);

    // ---- layer 3 ----
    gemm64_k<<<nb_gemm, TB, 0, stream>>>(aggF, b2, 1, W3, hwb, N);
    agg_csr_k<<<nb_agg, TB, 0, stream>>>(hwb, dis, offsets, csr_src, aggF, N);

    // ---- pool (2-stage) + final linear ----
    pool1_k<<<dim3(G, PSUB), TB, 0, stream>>>(aggF, gstart, partial);
    pool2_k<<<G, 64, 0, stream>>>(partial, gstart, b3, Wl, bl, out, O);
}

// Round 6
// 298.331 us; speedup vs baseline: 2.7625x; 1.2386x over previous
//
#include <hip/hip_runtime.h>

#define HD 64      // hidden/feature dim (D == H == 64)
#define PSUB 16    // sub-blocks per graph for pooling stage 1
#define NBLK 512   // histogram blocks (edge slices)
#define NBKT 512   // dst buckets (bucket = dst >> 7, 128 nodes each; N <= 65536)

// ---- bf16 helpers (manual, RNE) ----
__device__ __forceinline__ unsigned short f2bf(float f) {
    union { float f; unsigned u; } v; v.f = f;
    unsigned r = v.u + 0x7FFF + ((v.u >> 16) & 1);
    return (unsigned short)(r >> 16);
}
__device__ __forceinline__ float bf2f(unsigned short h) {
    union { unsigned u; float f; } v; v.u = ((unsigned)h) << 16;
    return v.f;
}

// ================= atomic-free bucketed CSR build =================

// 1) per-block LDS histogram of dst buckets; coalesced write hist[blk][bkt]
__global__ __launch_bounds__(256) void hist1_k(const int* __restrict__ dst,
                                               int* __restrict__ hist, int E, int chunk)
{
    __shared__ int lh[NBKT];
    int t = threadIdx.x;
    for (int i = t; i < NBKT; i += 256) lh[i] = 0;
    __syncthreads();
    int base = blockIdx.x * chunk;
    int end  = min(base + chunk, E);
    for (int i = base + t; i < end; i += 256)
        atomicAdd(&lh[dst[i] >> 7], 1);
    __syncthreads();
    for (int i = t; i < NBKT; i += 256)
        hist[blockIdx.x * NBKT + i] = lh[i];
}

// 2a) tile-reduce logical order l = bkt*NBLK + blk  (phys = blk*NBKT + bkt)
__global__ __launch_bounds__(256) void scanA_k(const int* __restrict__ hist,
                                               int* __restrict__ tsum)
{
    __shared__ int s[256];
    int t = threadIdx.x;
    int l = blockIdx.x * 256 + t;
    int phys = (l & (NBLK - 1)) * NBKT + (l >> 9);
    s[t] = hist[phys];
    __syncthreads();
    for (int off = 128; off > 0; off >>= 1) {
        if (t < off) s[t] += s[t + off];
        __syncthreads();
    }
    if (t == 0) tsum[blockIdx.x] = s[0];
}

// 2b) single block exclusive-scans tsum[0..nb)  (nb <= 1024)
__global__ __launch_bounds__(1024) void scanB_k(int* __restrict__ tsum, int nb)
{
    __shared__ int s[1024];
    int t = threadIdx.x;
    int v = (t < nb) ? tsum[t] : 0;
    s[t] = v;
    __syncthreads();
    for (int off = 1; off < 1024; off <<= 1) {
        int u = (t >= off) ? s[t - off] : 0;
        __syncthreads();
        s[t] += u;
        __syncthreads();
    }
    if (t < nb) tsum[t] = s[t] - v;
}

// 2c) local exclusive scan + tile base -> scanned[l] (logical layout, coalesced)
__global__ __launch_bounds__(256) void scanC_k(const int* __restrict__ hist,
                                               const int* __restrict__ tsum,
                                               int* __restrict__ scanned)
{
    __shared__ int s[256];
    int t = threadIdx.x;
    int l = blockIdx.x * 256 + t;
    int phys = (l & (NBLK - 1)) * NBKT + (l >> 9);
    int own = hist[phys];
    s[t] = own;
    __syncthreads();
    for (int off = 1; off < 256; off <<= 1) {
        int u = (t >= off) ? s[t - off] : 0;
        __syncthreads();
        s[t] += u;
        __syncthreads();
    }
    scanned[l] = tsum[blockIdx.x] + s[t] - own;
}

// 3) bucket-sorted append of (src,dst) pairs; per-block private ranges, no global atomics
__global__ __launch_bounds__(256) void append_k(const int* __restrict__ src,
    const int* __restrict__ dst, const int* __restrict__ scanned,
    int2* __restrict__ pairs, int E, int chunk)
{
    __shared__ int cur[NBKT];
    int t = threadIdx.x;
    int blk = blockIdx.x;
    for (int i = t; i < NBKT; i += 256) cur[i] = scanned[i * NBLK + blk];
    __syncthreads();
    int base = blk * chunk;
    int end  = min(base + chunk, E);
    for (int i = base + t; i < end; i += 256) {
        int s = src[i], d = dst[i];
        int p = atomicAdd(&cur[d >> 7], 1);
        pairs[p] = make_int2(s, d);
    }
}

// 4) per-bucket: node counts -> offsets/dis, then in-bucket scatter of csr_src
__global__ __launch_bounds__(256) void bucket_csr_k(const int2* __restrict__ pairs,
    const int* __restrict__ scanned, int* __restrict__ offsets,
    float* __restrict__ dis, int* __restrict__ csr_src, int N, int E)
{
    __shared__ int cnt[128];
    __shared__ int sc[128];
    __shared__ int cur[128];
    int t = threadIdx.x;
    int b = blockIdx.x;
    int nodeBase = b * 128;
    int nNodes = min(128, N - nodeBase);
    int bBase = scanned[b * NBLK];
    int bEnd  = (b + 1 < NBKT) ? scanned[(b + 1) * NBLK] : E;

    if (t < 128) cnt[t] = 0;
    __syncthreads();
    for (int i = bBase + t; i < bEnd; i += 256)
        atomicAdd(&cnt[pairs[i].y & 127], 1);
    __syncthreads();
    int myc = (t < 128) ? cnt[t] : 0;
    if (t < 128) sc[t] = myc;
    __syncthreads();
    for (int off = 1; off < 128; off <<= 1) {
        int u = (t < 128 && t >= off) ? sc[t - off] : 0;
        __syncthreads();
        if (t < 128) sc[t] += u;
        __syncthreads();
    }
    if (t < 128) {
        int excl = sc[t] - myc;
        cur[t] = excl;
        if (t < nNodes) {
            offsets[nodeBase + t] = bBase + excl;
            dis[nodeBase + t] = rsqrtf(1.0f + (float)myc);
        }
    }
    if (t == 0 && b == gridDim.x - 1) offsets[N] = E;
    __syncthreads();
    for (int i = bBase + t; i < bEnd; i += 256) {
        int2 pr = pairs[i];
        int pos = bBase + atomicAdd(&cur[pr.y & 127], 1);
        csr_src[pos] = pr.x;
    }
}

// ================= layers =================

// register-tiled 64x64 GEMM, bf16 output: out = act(in + b_prev) @ W
__global__ __launch_bounds__(256) void gemm64_k(
    const float* __restrict__ in, const float* __restrict__ b_prev, int relu_prev,
    const float* __restrict__ W, unsigned short* __restrict__ outb, int n)
{
    __shared__ float HsT[HD][68];   // [k][r], padded
    __shared__ float Ws[HD][HD];    // [k][c]
    int t = threadIdx.x;
    int rowBase = blockIdx.x * 64;

    for (int i = t; i < HD * HD / 4; i += 256)
        ((float4*)Ws)[i] = ((const float4*)W)[i];

    {
        int k0 = (t & 15) * 4;
        float4 bb = make_float4(0.f, 0.f, 0.f, 0.f);
        if (b_prev) bb = *(const float4*)&b_prev[k0];
        for (int it = 0; it < 4; ++it) {
            int r = (t >> 4) + it * 16;
            int row = rowBase + r;
            float4 v = make_float4(0.f, 0.f, 0.f, 0.f);
            if (row < n) {
                v = *(const float4*)&in[(size_t)row * HD + k0];
                v.x += bb.x; v.y += bb.y; v.z += bb.z; v.w += bb.w;
                if (relu_prev) {
                    v.x = fmaxf(v.x, 0.f); v.y = fmaxf(v.y, 0.f);
                    v.z = fmaxf(v.z, 0.f); v.w = fmaxf(v.w, 0.f);
                }
            }
            HsT[k0 + 0][r] = v.x;
            HsT[k0 + 1][r] = v.y;
            HsT[k0 + 2][r] = v.z;
            HsT[k0 + 3][r] = v.w;
        }
    }
    __syncthreads();

    int c4 = (t & 15) * 4;
    int r4 = (t >> 4) * 4;
    float acc[4][4];
    #pragma unroll
    for (int i = 0; i < 4; ++i)
        #pragma unroll
        for (int j = 0; j < 4; ++j) acc[i][j] = 0.f;

    #pragma unroll 8
    for (int k = 0; k < HD; ++k) {
        float4 a = *(const float4*)&HsT[k][r4];
        float4 b = *(const float4*)&Ws[k][c4];
        acc[0][0] += a.x * b.x; acc[0][1] += a.x * b.y; acc[0][2] += a.x * b.z; acc[0][3] += a.x * b.w;
        acc[1][0] += a.y * b.x; acc[1][1] += a.y * b.y; acc[1][2] += a.y * b.z; acc[1][3] += a.y * b.w;
        acc[2][0] += a.z * b.x; acc[2][1] += a.z * b.y; acc[2][2] += a.z * b.z; acc[2][3] += a.z * b.w;
        acc[3][0] += a.w * b.x; acc[3][1] += a.w * b.y; acc[3][2] += a.w * b.z; acc[3][3] += a.w * b.w;
    }

    #pragma unroll
    for (int i = 0; i < 4; ++i) {
        int row = rowBase + r4 + i;
        if (row < n) {
            ushort4 o;
            o.x = f2bf(acc[i][0]); o.y = f2bf(acc[i][1]);
            o.z = f2bf(acc[i][2]); o.w = f2bf(acc[i][3]);
            *(ushort4*)&outb[(size_t)row * HD + c4] = o;
        }
    }
}

// CSR gather-aggregate (bf16 hw): one wave per dst node
__global__ __launch_bounds__(256) void agg_csr_k(const unsigned short* __restrict__ hwb,
    const float* __restrict__ dis, const int* __restrict__ offsets,
    const int* __restrict__ csr_src, float* __restrict__ agg, int n)
{
    int wid  = (blockIdx.x * blockDim.x + threadIdx.x) >> 6;
    int lane = threadIdx.x & 63;
    if (wid >= n) return;
    float dn  = dis[wid];
    float acc = dn * dn * bf2f(hwb[(size_t)wid * HD + lane]);
    int beg = offsets[wid], end = offsets[wid + 1];
    int j = beg;
    for (; j + 2 <= end; j += 2) {
        int s0 = __builtin_amdgcn_readfirstlane(csr_src[j]);
        int s1 = __builtin_amdgcn_readfirstlane(csr_src[j + 1]);
        float h0 = bf2f(hwb[(size_t)s0 * HD + lane]);
        float h1 = bf2f(hwb[(size_t)s1 * HD + lane]);
        acc += dn * dis[s0] * h0;
        acc += dn * dis[s1] * h1;
    }
    if (j < end) {
        int s0 = __builtin_amdgcn_readfirstlane(csr_src[j]);
        acc += dn * dis[s0] * bf2f(hwb[(size_t)s0 * HD + lane]);
    }
    agg[(size_t)wid * HD + lane] = acc;
}

// graph segment starts (batch is sorted)
__global__ void gstart_k(const int* __restrict__ batch, int* __restrict__ gstart, int n, int G)
{
    int g = blockIdx.x * blockDim.x + threadIdx.x;
    if (g > G) return;
    if (g == G) { gstart[g] = n; return; }
    int lo = 0, hi = n;
    while (lo < hi) { int m = (lo + hi) >> 1; if (batch[m] < g) lo = m + 1; else hi = m; }
    gstart[g] = lo;
}

// pooling stage 1: per-(graph, sub-chunk) partial sums
__global__ __launch_bounds__(256) void pool1_k(const float* __restrict__ h,
    const int* __restrict__ gstart, float* __restrict__ partial)
{
    __shared__ float ps[4][HD];
    int g = blockIdx.x;
    int s = blockIdx.y;
    int t = threadIdx.x;
    int lane = t & 63;
    int w = t >> 6;
    int beg = gstart[g], end = gstart[g + 1];
    int len = end - beg;
    int c0 = beg + (int)(((long long)len * s) / PSUB);
    int c1 = beg + (int)(((long long)len * (s + 1)) / PSUB);
    float sum = 0.0f;
    for (int i = c0 + w; i < c1; i += 4) sum += h[(size_t)i * HD + lane];
    ps[w][lane] = sum;
    __syncthreads();
    if (t < HD)
        partial[((size_t)g * PSUB + s) * HD + t] = ps[0][t] + ps[1][t] + ps[2][t] + ps[3][t];
}

// pooling stage 2: reduce partials, mean + b3, final linear
__global__ __launch_bounds__(64) void pool2_k(const float* __restrict__ partial,
    const int* __restrict__ gstart, const float* __restrict__ b3,
    const float* __restrict__ Wl, const float* __restrict__ bl,
    float* __restrict__ out, int O)
{
    __shared__ float pooled[HD];
    int g = blockIdx.x;
    int t = threadIdx.x;
    float sum = 0.0f;
    #pragma unroll
    for (int s = 0; s < PSUB; ++s)
        sum += partial[((size_t)g * PSUB + s) * HD + t];
    float cnt = (float)(gstart[g + 1] - gstart[g]);
    pooled[t] = sum / cnt + b3[t];
    __syncthreads();
    if (t < O) {
        float acc = bl[t];
        #pragma unroll
        for (int k = 0; k < HD; ++k) acc += pooled[k] * Wl[k * O + t];
        out[g * O + t] = acc;
    }
}

extern "C" void kernel_launch(void* const* d_in, const int* in_sizes, int n_in,
                              void* d_out, int out_size, void* d_ws, size_t ws_size,
                              hipStream_t stream)
{
    const float* x    = (const float*)d_in[0];
    const int*   ei   = (const int*)d_in[1];
    const int*   batch= (const int*)d_in[2];
    const float* W1   = (const float*)d_in[3];
    const float* b1   = (const float*)d_in[4];
    const float* W2   = (const float*)d_in[5];
    const float* b2   = (const float*)d_in[6];
    const float* W3   = (const float*)d_in[7];
    const float* b3   = (const float*)d_in[8];
    const float* Wl   = (const float*)d_in[9];
    const float* bl   = (const float*)d_in[10];
    float* out = (float*)d_out;

    const int N = in_sizes[0] / HD;
    const int E = in_sizes[1] / 2;
    const int O = in_sizes[10];
    const int G = out_size / O;

    const int* src = ei;        // edge_index[0]
    const int* dst = ei + E;    // edge_index[1]

    // ---- workspace layout (256 B aligned) ----
    char* p = (char*)d_ws;
    auto take = [&](size_t bytes) { char* r = p; p += (bytes + 255) & ~(size_t)255; return r; };
    int*   csr_src = (int*)  take((size_t)E * 4);
    int*   offsets = (int*)  take((size_t)(N + 1) * 4);
    float* dis     = (float*)take((size_t)N * 4);
    int*   gstart  = (int*)  take((size_t)(G + 1) * 4);
    float* partial = (float*)take((size_t)G * PSUB * HD * 4);
    float* aggF    = (float*)take((size_t)N * HD * 4);       // 12.8 MB
    unsigned short* hwb = (unsigned short*)take((size_t)N * HD * 2);  // 6.4 MB

    // aliases into regions not yet live during CSR build:
    int*  hist    = (int*)aggF;                       // 1 MB   (NBLK*NBKT)
    int*  scanned = hist + NBLK * NBKT;               // 1 MB
    int*  tsum    = scanned + NBLK * NBKT;            // 4 KB
    int2* pairs   = (int2*)hwb;                       // E*8 = 6.4 MB (== hwb size)

    const int TB = 256;
    int chunk   = (E + NBLK - 1) / NBLK;
    int ntiles  = (NBLK * NBKT) / 256;                // 1024
    int nb_gemm = (N + 63) / 64;
    int nb_agg  = (N * 64 + TB - 1) / TB;
    int nbuck   = (N + 127) / 128;

    // ---- CSR build (atomic-free counting sort) ----
    hist1_k<<<NBLK, TB, 0, stream>>>(dst, hist, E, chunk);
    scanA_k<<<ntiles, TB, 0, stream>>>(hist, tsum);
    scanB_k<<<1, 1024, 0, stream>>>(tsum, ntiles);
    scanC_k<<<ntiles, TB, 0, stream>>>(hist, tsum, scanned);
    append_k<<<NBLK, TB, 0, stream>>>(src, dst, scanned, pairs, E, chunk);
    bucket_csr_k<<<nbuck, TB, 0, stream>>>(pairs, scanned, offsets, dis, csr_src, N, E);
    gstart_k<<<1, 128, 0, stream>>>(batch, gstart, N, G);

    // ---- layer 1 ----
    gemm64_k<<<nb_gemm, TB, 0, stream>>>(x, nullptr, 0, W1, hwb, N);
    agg_csr_k<<<nb_agg, TB, 0, stream>>>(hwb, dis, offsets, csr_src, aggF, N);

    // ---- layer 2 ----
    gemm64_k<<<nb_gemm, TB, 0, stream>>>(aggF, b1, 1, W2, hwb, N);
    agg_csr_k<<<nb_agg, TB, 0, stream>>>(hwb, dis, offsets, csr_src, aggF, N);

    // ---- layer 3 ----
    gemm64_k<<<nb_gemm, TB, 0, stream>>>(aggF, b2, 1, W3, hwb, N);
    agg_csr_k<<<nb_agg, TB, 0, stream>>>(hwb, dis, offsets, csr_src, aggF, N);

    // ---- pool (2-stage) + final linear ----
    pool1_k<<<dim3(G, PSUB), TB, 0, stream>>>(aggF, gstart, partial);
    pool2_k<<<G, 64, 0, stream>>>(partial, gstart, b3, Wl, bl, out, O);
}

// Round 7
// 257.566 us; speedup vs baseline: 3.1997x; 1.1583x over previous
//
#include <hip/hip_runtime.h>

#define HD 64      // hidden/feature dim (D == H == 64)
#define PSUB 16    // sub-blocks per graph for pooling stage 1
#define NBLK 512   // histogram blocks (edge slices)
#define NBKT 512   // dst buckets (bucket = dst >> 7, 128 nodes each; N <= 65536)

// ---- bf16 helpers (manual, RNE) ----
__device__ __forceinline__ unsigned short f2bf(float f) {
    union { float f; unsigned u; } v; v.f = f;
    unsigned r = v.u + 0x7FFF + ((v.u >> 16) & 1);
    return (unsigned short)(r >> 16);
}
__device__ __forceinline__ float bf2f(unsigned short h) {
    union { unsigned u; float f; } v; v.u = ((unsigned)h) << 16;
    return v.f;
}
__device__ __forceinline__ int rdlane(int v, int l) {
    return __builtin_amdgcn_readlane(v, l);
}
__device__ __forceinline__ float rdlanef(float v, int l) {
    union { float f; int i; } u; u.f = v;
    u.i = __builtin_amdgcn_readlane(u.i, l);
    return u.f;
}

// ================= atomic-free bucketed CSR build =================

// 1) per-block LDS histogram of dst buckets; coalesced write hist[blk][bkt]
__global__ __launch_bounds__(256) void hist1_k(const int* __restrict__ dst,
                                               int* __restrict__ hist, int E, int chunk)
{
    __shared__ int lh[NBKT];
    int t = threadIdx.x;
    for (int i = t; i < NBKT; i += 256) lh[i] = 0;
    __syncthreads();
    int base = blockIdx.x * chunk;
    int end  = min(base + chunk, E);
    for (int i = base + t; i < end; i += 256)
        atomicAdd(&lh[dst[i] >> 7], 1);
    __syncthreads();
    for (int i = t; i < NBKT; i += 256)
        hist[blockIdx.x * NBKT + i] = lh[i];
}

// 2a) tile-reduce logical order l = bkt*NBLK + blk  (phys = blk*NBKT + bkt)
__global__ __launch_bounds__(256) void scanA_k(const int* __restrict__ hist,
                                               int* __restrict__ tsum)
{
    __shared__ int s[256];
    int t = threadIdx.x;
    int l = blockIdx.x * 256 + t;
    int phys = (l & (NBLK - 1)) * NBKT + (l >> 9);
    s[t] = hist[phys];
    __syncthreads();
    for (int off = 128; off > 0; off >>= 1) {
        if (t < off) s[t] += s[t + off];
        __syncthreads();
    }
    if (t == 0) tsum[blockIdx.x] = s[0];
}

// 2b) single block exclusive-scans tsum[0..nb)  (nb <= 1024)
__global__ __launch_bounds__(1024) void scanB_k(int* __restrict__ tsum, int nb)
{
    __shared__ int s[1024];
    int t = threadIdx.x;
    int v = (t < nb) ? tsum[t] : 0;
    s[t] = v;
    __syncthreads();
    for (int off = 1; off < 1024; off <<= 1) {
        int u = (t >= off) ? s[t - off] : 0;
        __syncthreads();
        s[t] += u;
        __syncthreads();
    }
    if (t < nb) tsum[t] = s[t] - v;
}

// 2c) local exclusive scan + tile base -> scanned[l] (logical layout, coalesced)
__global__ __launch_bounds__(256) void scanC_k(const int* __restrict__ hist,
                                               const int* __restrict__ tsum,
                                               int* __restrict__ scanned)
{
    __shared__ int s[256];
    int t = threadIdx.x;
    int l = blockIdx.x * 256 + t;
    int phys = (l & (NBLK - 1)) * NBKT + (l >> 9);
    int own = hist[phys];
    s[t] = own;
    __syncthreads();
    for (int off = 1; off < 256; off <<= 1) {
        int u = (t >= off) ? s[t - off] : 0;
        __syncthreads();
        s[t] += u;
        __syncthreads();
    }
    scanned[l] = tsum[blockIdx.x] + s[t] - own;
}

// 3) bucket-sorted append of (src,dst) pairs; per-block private ranges, no global atomics
__global__ __launch_bounds__(256) void append_k(const int* __restrict__ src,
    const int* __restrict__ dst, const int* __restrict__ scanned,
    int2* __restrict__ pairs, int E, int chunk)
{
    __shared__ int cur[NBKT];
    int t = threadIdx.x;
    int blk = blockIdx.x;
    for (int i = t; i < NBKT; i += 256) cur[i] = scanned[i * NBLK + blk];
    __syncthreads();
    int base = blk * chunk;
    int end  = min(base + chunk, E);
    for (int i = base + t; i < end; i += 256) {
        int s = src[i], d = dst[i];
        int p = atomicAdd(&cur[d >> 7], 1);
        pairs[p] = make_int2(s, d);
    }
}

// 4) per-bucket: node counts -> offsets/dis, then in-bucket scatter of csr_src
__global__ __launch_bounds__(256) void bucket_csr_k(const int2* __restrict__ pairs,
    const int* __restrict__ scanned, int* __restrict__ offsets,
    float* __restrict__ dis, int* __restrict__ csr_src, int N, int E)
{
    __shared__ int cnt[128];
    __shared__ int sc[128];
    __shared__ int cur[128];
    int t = threadIdx.x;
    int b = blockIdx.x;
    int nodeBase = b * 128;
    int nNodes = min(128, N - nodeBase);
    int bBase = scanned[b * NBLK];
    int bEnd  = (b + 1 < NBKT) ? scanned[(b + 1) * NBLK] : E;

    if (t < 128) cnt[t] = 0;
    __syncthreads();
    for (int i = bBase + t; i < bEnd; i += 256)
        atomicAdd(&cnt[pairs[i].y & 127], 1);
    __syncthreads();
    int myc = (t < 128) ? cnt[t] : 0;
    if (t < 128) sc[t] = myc;
    __syncthreads();
    for (int off = 1; off < 128; off <<= 1) {
        int u = (t < 128 && t >= off) ? sc[t - off] : 0;
        __syncthreads();
        if (t < 128) sc[t] += u;
        __syncthreads();
    }
    if (t < 128) {
        int excl = sc[t] - myc;
        cur[t] = excl;
        if (t < nNodes) {
            offsets[nodeBase + t] = bBase + excl;
            dis[nodeBase + t] = rsqrtf(1.0f + (float)myc);
        }
    }
    if (t == 0 && b == gridDim.x - 1) offsets[N] = E;
    __syncthreads();
    for (int i = bBase + t; i < bEnd; i += 256) {
        int2 pr = pairs[i];
        int pos = bBase + atomicAdd(&cur[pr.y & 127], 1);
        csr_src[pos] = pr.x;
    }
}

// ================= layers =================

// register-tiled 64x64 GEMM, bf16 output: out = act(in + b_prev) @ W
__global__ __launch_bounds__(256) void gemm64_k(
    const float* __restrict__ in, const float* __restrict__ b_prev, int relu_prev,
    const float* __restrict__ W, unsigned short* __restrict__ outb, int n)
{
    __shared__ float HsT[HD][68];   // [k][r], padded
    __shared__ float Ws[HD][HD];    // [k][c]
    int t = threadIdx.x;
    int rowBase = blockIdx.x * 64;

    for (int i = t; i < HD * HD / 4; i += 256)
        ((float4*)Ws)[i] = ((const float4*)W)[i];

    {
        int k0 = (t & 15) * 4;
        float4 bb = make_float4(0.f, 0.f, 0.f, 0.f);
        if (b_prev) bb = *(const float4*)&b_prev[k0];
        for (int it = 0; it < 4; ++it) {
            int r = (t >> 4) + it * 16;
            int row = rowBase + r;
            float4 v = make_float4(0.f, 0.f, 0.f, 0.f);
            if (row < n) {
                v = *(const float4*)&in[(size_t)row * HD + k0];
                v.x += bb.x; v.y += bb.y; v.z += bb.z; v.w += bb.w;
                if (relu_prev) {
                    v.x = fmaxf(v.x, 0.f); v.y = fmaxf(v.y, 0.f);
                    v.z = fmaxf(v.z, 0.f); v.w = fmaxf(v.w, 0.f);
                }
            }
            HsT[k0 + 0][r] = v.x;
            HsT[k0 + 1][r] = v.y;
            HsT[k0 + 2][r] = v.z;
            HsT[k0 + 3][r] = v.w;
        }
    }
    __syncthreads();

    int c4 = (t & 15) * 4;
    int r4 = (t >> 4) * 4;
    float acc[4][4];
    #pragma unroll
    for (int i = 0; i < 4; ++i)
        #pragma unroll
        for (int j = 0; j < 4; ++j) acc[i][j] = 0.f;

    #pragma unroll 8
    for (int k = 0; k < HD; ++k) {
        float4 a = *(const float4*)&HsT[k][r4];
        float4 b = *(const float4*)&Ws[k][c4];
        acc[0][0] += a.x * b.x; acc[0][1] += a.x * b.y; acc[0][2] += a.x * b.z; acc[0][3] += a.x * b.w;
        acc[1][0] += a.y * b.x; acc[1][1] += a.y * b.y; acc[1][2] += a.y * b.z; acc[1][3] += a.y * b.w;
        acc[2][0] += a.z * b.x; acc[2][1] += a.z * b.y; acc[2][2] += a.z * b.z; acc[2][3] += a.z * b.w;
        acc[3][0] += a.w * b.x; acc[3][1] += a.w * b.y; acc[3][2] += a.w * b.z; acc[3][3] += a.w * b.w;
    }

    #pragma unroll
    for (int i = 0; i < 4; ++i) {
        int row = rowBase + r4 + i;
        if (row < n) {
            ushort4 o;
            o.x = f2bf(acc[i][0]); o.y = f2bf(acc[i][1]);
            o.z = f2bf(acc[i][2]); o.w = f2bf(acc[i][3]);
            *(ushort4*)&outb[(size_t)row * HD + c4] = o;
        }
    }
}

// CSR gather-aggregate (bf16 hw): one wave per dst node.
// Edge indices + dis are prefetched lane-strided into registers, then
// broadcast via v_readlane -> inner loop has ONE independent gather per edge,
// issued 4-deep (tail clamped with zero weights to keep 4 in flight).
__global__ __launch_bounds__(256) void agg_csr_k(const unsigned short* __restrict__ hwb,
    const float* __restrict__ dis, const int* __restrict__ offsets,
    const int* __restrict__ csr_src, float* __restrict__ agg, int n)
{
    int wid  = (blockIdx.x * blockDim.x + threadIdx.x) >> 6;
    int lane = threadIdx.x & 63;
    if (wid >= n) return;
    float dn  = dis[wid];
    float acc = dn * dn * bf2f(hwb[(size_t)wid * HD + lane]);
    int beg = offsets[wid], end = offsets[wid + 1];

    for (int base = beg; base < end; base += 64) {
        int m = min(64, end - base);
        int idx = 0;
        float dv = 0.f;
        if (lane < m) {
            idx = csr_src[base + lane];   // coalesced 256B
            dv  = dis[idx];               // 4B gather
        }
        for (int j = 0; j < m; j += 4) {
            int j1 = min(j + 1, m - 1), j2 = min(j + 2, m - 1), j3 = min(j + 3, m - 1);
            int s0 = rdlane(idx, j),  s1 = rdlane(idx, j1);
            int s2 = rdlane(idx, j2), s3 = rdlane(idx, j3);
            float w0 = dn * rdlanef(dv, j);
            float w1 = (j + 1 < m) ? dn * rdlanef(dv, j1) : 0.f;
            float w2 = (j + 2 < m) ? dn * rdlanef(dv, j2) : 0.f;
            float w3 = (j + 3 < m) ? dn * rdlanef(dv, j3) : 0.f;
            float h0 = bf2f(hwb[(size_t)s0 * HD + lane]);
            float h1 = bf2f(hwb[(size_t)s1 * HD + lane]);
            float h2 = bf2f(hwb[(size_t)s2 * HD + lane]);
            float h3 = bf2f(hwb[(size_t)s3 * HD + lane]);
            acc += w0 * h0;
            acc += w1 * h1;
            acc += w2 * h2;
            acc += w3 * h3;
        }
    }
    agg[(size_t)wid * HD + lane] = acc;
}

// graph segment starts (batch is sorted)
__global__ void gstart_k(const int* __restrict__ batch, int* __restrict__ gstart, int n, int G)
{
    int g = blockIdx.x * blockDim.x + threadIdx.x;
    if (g > G) return;
    if (g == G) { gstart[g] = n; return; }
    int lo = 0, hi = n;
    while (lo < hi) { int m = (lo + hi) >> 1; if (batch[m] < g) lo = m + 1; else hi = m; }
    gstart[g] = lo;
}

// pooling stage 1: per-(graph, sub-chunk) partial sums
__global__ __launch_bounds__(256) void pool1_k(const float* __restrict__ h,
    const int* __restrict__ gstart, float* __restrict__ partial)
{
    __shared__ float ps[4][HD];
    int g = blockIdx.x;
    int s = blockIdx.y;
    int t = threadIdx.x;
    int lane = t & 63;
    int w = t >> 6;
    int beg = gstart[g], end = gstart[g + 1];
    int len = end - beg;
    int c0 = beg + (int)(((long long)len * s) / PSUB);
    int c1 = beg + (int)(((long long)len * (s + 1)) / PSUB);
    float sum = 0.0f;
    for (int i = c0 + w; i < c1; i += 4) sum += h[(size_t)i * HD + lane];
    ps[w][lane] = sum;
    __syncthreads();
    if (t < HD)
        partial[((size_t)g * PSUB + s) * HD + t] = ps[0][t] + ps[1][t] + ps[2][t] + ps[3][t];
}

// pooling stage 2: reduce partials, mean + b3, final linear
__global__ __launch_bounds__(64) void pool2_k(const float* __restrict__ partial,
    const int* __restrict__ gstart, const float* __restrict__ b3,
    const float* __restrict__ Wl, const float* __restrict__ bl,
    float* __restrict__ out, int O)
{
    __shared__ float pooled[HD];
    int g = blockIdx.x;
    int t = threadIdx.x;
    float sum = 0.0f;
    #pragma unroll
    for (int s = 0; s < PSUB; ++s)
        sum += partial[((size_t)g * PSUB + s) * HD + t];
    float cnt = (float)(gstart[g + 1] - gstart[g]);
    pooled[t] = sum / cnt + b3[t];
    __syncthreads();
    if (t < O) {
        float acc = bl[t];
        #pragma unroll
        for (int k = 0; k < HD; ++k) acc += pooled[k] * Wl[k * O + t];
        out[g * O + t] = acc;
    }
}

extern "C" void kernel_launch(void* const* d_in, const int* in_sizes, int n_in,
                              void* d_out, int out_size, void* d_ws, size_t ws_size,
                              hipStream_t stream)
{
    const float* x    = (const float*)d_in[0];
    const int*   ei   = (const int*)d_in[1];
    const int*   batch= (const int*)d_in[2];
    const float* W1   = (const float*)d_in[3];
    const float* b1   = (const float*)d_in[4];
    const float* W2   = (const float*)d_in[5];
    const float* b2   = (const float*)d_in[6];
    const float* W3   = (const float*)d_in[7];
    const float* b3   = (const float*)d_in[8];
    const float* Wl   = (const float*)d_in[9];
    const float* bl   = (const float*)d_in[10];
    float* out = (float*)d_out;

    const int N = in_sizes[0] / HD;
    const int E = in_sizes[1] / 2;
    const int O = in_sizes[10];
    const int G = out_size / O;

    const int* src = ei;        // edge_index[0]
    const int* dst = ei + E;    // edge_index[1]

    // ---- workspace layout (256 B aligned) ----
    char* p = (char*)d_ws;
    auto take = [&](size_t bytes) { char* r = p; p += (bytes + 255) & ~(size_t)255; return r; };
    int*   csr_src = (int*)  take((size_t)E * 4);
    int*   offsets = (int*)  take((size_t)(N + 1) * 4);
    float* dis     = (float*)take((size_t)N * 4);
    int*   gstart  = (int*)  take((size_t)(G + 1) * 4);
    float* partial = (float*)take((size_t)G * PSUB * HD * 4);
    float* aggF    = (float*)take((size_t)N * HD * 4);       // 12.8 MB
    unsigned short* hwb = (unsigned short*)take((size_t)N * HD * 2);  // 6.4 MB

    // aliases into regions not yet live during CSR build:
    int*  hist    = (int*)aggF;                       // 1 MB   (NBLK*NBKT)
    int*  scanned = hist + NBLK * NBKT;               // 1 MB
    int*  tsum    = scanned + NBLK * NBKT;            // 4 KB
    int2* pairs   = (int2*)hwb;                       // E*8 = 6.4 MB (== hwb size)

    const int TB = 256;
    int chunk   = (E + NBLK - 1) / NBLK;
    int ntiles  = (NBLK * NBKT) / 256;                // 1024
    int nb_gemm = (N + 63) / 64;
    int nb_agg  = (N * 64 + TB - 1) / TB;
    int nbuck   = (N + 127) / 128;

    // ---- CSR build (atomic-free counting sort) ----
    hist1_k<<<NBLK, TB, 0, stream>>>(dst, hist, E, chunk);
    scanA_k<<<ntiles, TB, 0, stream>>>(hist, tsum);
    scanB_k<<<1, 1024, 0, stream>>>(tsum, ntiles);
    scanC_k<<<ntiles, TB, 0, stream>>>(hist, tsum, scanned);
    append_k<<<NBLK, TB, 0, stream>>>(src, dst, scanned, pairs, E, chunk);
    bucket_csr_k<<<nbuck, TB, 0, stream>>>(pairs, scanned, offsets, dis, csr_src, N, E);
    gstart_k<<<1, 128, 0, stream>>>(batch, gstart, N, G);

    // ---- layer 1 ----
    gemm64_k<<<nb_gemm, TB, 0, stream>>>(x, nullptr, 0, W1, hwb, N);
    agg_csr_k<<<nb_agg, TB, 0, stream>>>(hwb, dis, offsets, csr_src, aggF, N);

    // ---- layer 2 ----
    gemm64_k<<<nb_gemm, TB, 0, stream>>>(aggF, b1, 1, W2, hwb, N);
    agg_csr_k<<<nb_agg, TB, 0, stream>>>(hwb, dis, offsets, csr_src, aggF, N);

    // ---- layer 3 ----
    gemm64_k<<<nb_gemm, TB, 0, stream>>>(aggF, b2, 1, W3, hwb, N);
    agg_csr_k<<<nb_agg, TB, 0, stream>>>(hwb, dis, offsets, csr_src, aggF, N);

    // ---- pool (2-stage) + final linear ----
    pool1_k<<<dim3(G, PSUB), TB, 0, stream>>>(aggF, gstart, partial);
    pool2_k<<<G, 64, 0, stream>>>(partial, gstart, b3, Wl, bl, out, O);
}